// Round 9
// baseline (989.723 us; speedup 1.0000x reference)
//
#include <hip/hip_runtime.h>
#include <hip/hip_bf16.h>

#define MROWS 4096      // B*T
#define KDIM 1024       // H
#define NVOCAB 32000    // V
#define BM 128
#define BN 256
#define BK 32
#define NTILES (NVOCAB / BN)   // 125
#define KT (KDIM / BK)         // 32
#define BETA 0.1f

typedef __attribute__((ext_vector_type(8))) short s8v;
typedef __attribute__((ext_vector_type(4))) float f4v;

__device__ inline void gload16(const void* g, void* l) {
  __builtin_amdgcn_global_load_lds(
      (const __attribute__((address_space(1))) void*)g,
      (__attribute__((address_space(3))) void*)l, 16, 0, 0);
}

__device__ inline unsigned bf16pair(float lo, float hi) {
  unsigned a = __float_as_uint(lo), b = __float_as_uint(hi);
  a = (a + 0x7FFFu + ((a >> 16) & 1u)) >> 16;
  b = (b + 0x7FFFu + ((b >> 16) & 1u)) >> 16;
  return a | (b << 16);
}

// fused fp32 -> bf16 (RNE) for all 4 tensors, grid-stride, 16B/load
__global__ void cvt_all(const float4* __restrict__ x, const float4* __restrict__ rx,
                        const float4* __restrict__ W, const float4* __restrict__ rW,
                        uint4* __restrict__ xb, uint4* __restrict__ rxb,
                        uint4* __restrict__ Wb, uint4* __restrict__ rWb) {
  const int NX = MROWS * KDIM / 8;      // 524288
  const int NW = NVOCAB * KDIM / 8;     // 4096000
  const int total = 2 * NX + 2 * NW;
  for (int i = blockIdx.x * 256 + threadIdx.x; i < total; i += gridDim.x * 256) {
    const float4* s; uint4* d; int j;
    if (i < NX)               { s = x;  d = xb;  j = i; }
    else if (i < 2 * NX)      { s = rx; d = rxb; j = i - NX; }
    else if (i < 2 * NX + NW) { s = W;  d = Wb;  j = i - 2 * NX; }
    else                      { s = rW; d = rWb; j = i - 2 * NX - NW; }
    float4 a = s[2 * j], b = s[2 * j + 1];
    uint4 o;
    o.x = bf16pair(a.x, a.y);
    o.y = bf16pair(a.z, a.w);
    o.z = bf16pair(b.x, b.y);
    o.w = bf16pair(b.z, b.w);
    d[j] = o;
  }
}

// 128x256 GEMM tile, 4 waves (each 128x64 out: 12 ds_read per 32 MFMA),
// BK=32, 2-slot LDS ring (53 KB, <=256 regs/wave -> TWO blocks per CU:
// independent barrier domains overlap LDS phase of one block with MFMA
// phase of the other). One vmcnt(0)+barrier trail per group.
// LDS fragment-contiguous: K-tile = blocks of 1024B (16 rows x 32k); lane l
// owns row (l&15), k (l>>4)*8..+8 -> ds_read_b128 uniform base + imm.
// grid = (4000, 2 models), block = 256
__global__ __launch_bounds__(256, 2) void gemm_lse(
    const __hip_bfloat16* __restrict__ xb, const __hip_bfloat16* __restrict__ rxb,
    const __hip_bfloat16* __restrict__ Wb, const __hip_bfloat16* __restrict__ rWb,
    const int* __restrict__ y,
    float2* __restrict__ partials,  // [2][NTILES][MROWS]
    float* __restrict__ tgt)        // [2][MROWS]
{
  const int bid = blockIdx.x;       // 0..3999
  const int bz  = blockIdx.y;       // model
  // XCD banding: XCD x owns mtiles x*4..x*4+3, sweeps ntiles (W panel reuse)
  const int xcd   = bid & 7;
  const int idx   = bid >> 3;       // 0..499
  const int ntile = idx >> 2;       // 0..124
  const int mtile = xcd * 4 + (idx & 3);
  const int m0 = mtile * BM, n0 = ntile * BN;

  const __hip_bfloat16* A  = bz ? rxb : xb;
  const __hip_bfloat16* Bw = bz ? rWb : Wb;

  const int tid = threadIdx.x;
  const int lane = tid & 63;
  const int wc = tid >> 6;           // 0..3 : wave owns cols wc*64..+63
  const int l15 = lane & 15, l4 = lane >> 4;

  __shared__ __align__(16) short As[2][BM * BK];   // 2 x 8 KB
  __shared__ __align__(16) short Bs[2][BN * BK];   // 2 x 16 KB
  __shared__ int ys[BM];
  __shared__ float redM[4][BM];
  __shared__ float redS[4][BM];

  if (tid < BM) ys[tid] = y[m0 + tid];

  f4v acc[8][4];
#pragma unroll
  for (int i = 0; i < 8; ++i)
#pragma unroll
    for (int j = 0; j < 4; ++j) acc[i][j] = (f4v){0.f, 0.f, 0.f, 0.f};

  // staging source map: chunk c (16B) -> LDS short idx c*8; block b=c>>6 holds
  // rows b*16..+15; pos p=c&63: row b*16+(p&15), k ((p>>4)&3)*8.
  // A tile 8KB: chunks c=tid, tid+256 (2 gloads); B 16KB: c=tid+j*256, j=0..3.
  const int prow = ((tid >> 6) & 3) * 16 + (tid & 15);
  const int pcol = ((tid >> 4) & 3) * 8;
  const __hip_bfloat16* sA = A  + (size_t)(m0 + prow) * KDIM + pcol;
  const __hip_bfloat16* sB = Bw + (size_t)(n0 + prow) * KDIM + pcol;
  const size_t rstep = (size_t)64 * KDIM;

#define STAGE(koff, s)                                                    \
  {                                                                       \
    gload16(sA + (koff),         &As[s][tid * 8]);                        \
    gload16(sA + (koff) + rstep, &As[s][tid * 8 + 2048]);                 \
    _Pragma("unroll")                                                     \
    for (int j = 0; j < 4; ++j)                                           \
      gload16(sB + (koff) + j * rstep, &Bs[s][tid * 8 + j * 2048]);       \
  }

  // prologue: stage tile 0 -> slot 0
  STAGE(0, 0);
  asm volatile("s_waitcnt vmcnt(0)" ::: "memory");
  __builtin_amdgcn_s_barrier();

  // Group t: read slot t&1 (12 ds_read_b128/wave), stage tile t+1 -> other
  // slot (6 gloads/thread), 32 MFMA; trail vmcnt(0)+barrier (other resident
  // block covers the drain).
#pragma unroll 1
  for (int t = 0; t < KT; ++t) {
    const short* Sa = &As[t & 1][lane * 8];
    const short* Sb = &Bs[t & 1][wc * 2048 + lane * 8];
    s8v af[8], bf[4];
#pragma unroll
    for (int mi = 0; mi < 8; ++mi) af[mi] = *(const s8v*)(Sa + mi * 512);
#pragma unroll
    for (int ni = 0; ni < 4; ++ni) bf[ni] = *(const s8v*)(Sb + ni * 512);
    if (t < KT - 1) STAGE((t + 1) * BK, (t + 1) & 1);
#pragma unroll
    for (int mi = 0; mi < 8; ++mi)
#pragma unroll
      for (int ni = 0; ni < 4; ++ni)
        acc[mi][ni] = __builtin_amdgcn_mfma_f32_16x16x32_bf16(
            af[mi], bf[ni], acc[mi][ni], 0, 0, 0);
    if (t < KT - 1) {
      asm volatile("s_waitcnt vmcnt(0)" ::: "memory");
      __builtin_amdgcn_s_barrier();
    }
  }
#undef STAGE

  // Epilogue: per-row (max, sumexp) over this block's 256 cols + target gather.
  // 16x16 D layout: row = mi*16 + l4*4 + r, col = wc*64 + ni*16 + l15
#pragma unroll
  for (int mi = 0; mi < 8; ++mi) {
#pragma unroll
    for (int r = 0; r < 4; ++r) {
      float v0 = acc[mi][0][r], v1 = acc[mi][1][r], v2 = acc[mi][2][r], v3 = acc[mi][3][r];
      float mx = fmaxf(fmaxf(v0, v1), fmaxf(v2, v3));
#pragma unroll
      for (int d = 1; d < 16; d <<= 1) mx = fmaxf(mx, __shfl_xor(mx, d));
      float ex = __expf(v0 - mx) + __expf(v1 - mx) + __expf(v2 - mx) + __expf(v3 - mx);
#pragma unroll
      for (int d = 1; d < 16; d <<= 1) ex += __shfl_xor(ex, d);
      int rowInBlock = mi * 16 + l4 * 4 + r;
      if (l15 == 0) { redM[wc][rowInBlock] = mx; redS[wc][rowInBlock] = ex; }
      int yv = ys[rowInBlock];
      int cl = yv - (n0 + wc * 64);
      if (cl >= 0 && cl < 64 && (cl & 15) == l15) {
        int ni = cl >> 4;
        float tv = ni == 0 ? v0 : ni == 1 ? v1 : ni == 2 ? v2 : v3;
        tgt[(size_t)bz * MROWS + m0 + rowInBlock] = tv;
      }
    }
  }
  __syncthreads();
  if (tid < BM) {
    float M = redM[0][tid], S = redS[0][tid];
#pragma unroll
    for (int c = 1; c < 4; ++c) {
      float m2 = redM[c][tid], s2 = redS[c][tid];
      float Mn = fmaxf(M, m2);
      S = S * __expf(M - Mn) + s2 * __expf(m2 - Mn);
      M = Mn;
    }
    partials[((size_t)bz * NTILES + ntile) * MROWS + m0 + tid] = make_float2(M, S);
  }
}

// merge partials per row -> lse -> per-example mean target logp
__global__ void rowred(const float2* __restrict__ partials, const float* __restrict__ tgt,
                       const int* __restrict__ y, float* __restrict__ logps) {
  const int model = blockIdx.x >> 2;
  const int b = blockIdx.x & 3;
  const int tid = threadIdx.x;
  float sum = 0.f, cnt = 0.f;
  for (int t = tid; t < 1024; t += 256) {
    const int row = b * 1024 + t;
    float M = -INFINITY, S = 0.f;
    for (int j = 0; j < NTILES; ++j) {
      float2 v = partials[((size_t)model * NTILES + j) * MROWS + row];
      float Mn = fmaxf(M, v.x);
      S = S * __expf(M - Mn) + v.y * __expf(v.x - Mn);
      M = Mn;
    }
    int yv = y[row];
    if (yv != -100) {
      sum += tgt[(size_t)model * MROWS + row] - (M + __logf(S));
      cnt += 1.f;
    }
  }
  __shared__ float sS[4], sC[4];
#pragma unroll
  for (int d = 1; d < 64; d <<= 1) { sum += __shfl_xor(sum, d); cnt += __shfl_xor(cnt, d); }
  int w = tid >> 6;
  if ((tid & 63) == 0) { sS[w] = sum; sC[w] = cnt; }
  __syncthreads();
  if (tid == 0) {
    float s = 0.f, c = 0.f;
    for (int i = 0; i < 4; ++i) { s += sS[i]; c += sC[i]; }
    logps[blockIdx.x] = s / c;
  }
}

__global__ void finalk(const float* __restrict__ logps, const int* __restrict__ pref,
                       float* __restrict__ out) {
  if (threadIdx.x == 0 && blockIdx.x == 0) {
    float acc = 0.f;
    for (int b = 0; b < 4; ++b) {
      float lr = logps[b] - logps[4 + b];   // policy - ref
      float z = BETA * lr;
      float sig = 1.f / (1.f + __expf(-z));
      acc += (pref[b] != 0) ? (1.f - sig) : sig;
    }
    out[0] = acc * 0.25f;
  }
}

extern "C" void kernel_launch(void* const* d_in, const int* in_sizes, int n_in,
                              void* d_out, int out_size, void* d_ws, size_t ws_size,
                              hipStream_t stream) {
  const float* x    = (const float*)d_in[0];
  const float* rx   = (const float*)d_in[1];
  const int*   y    = (const int*)d_in[2];
  const int*   pref = (const int*)d_in[3];
  const float* W    = (const float*)d_in[4];
  const float* rW   = (const float*)d_in[5];
  float* out = (float*)d_out;

  char* ws = (char*)d_ws;
  const size_t SZ_X = (size_t)MROWS * KDIM * 2;        // 8,388,608
  const size_t SZ_W = (size_t)NVOCAB * KDIM * 2;       // 65,536,000
  __hip_bfloat16* xb   = (__hip_bfloat16*)(ws);
  __hip_bfloat16* rxb  = (__hip_bfloat16*)(ws + SZ_X);
  __hip_bfloat16* Wb   = (__hip_bfloat16*)(ws + 2 * SZ_X);
  __hip_bfloat16* rWb  = (__hip_bfloat16*)(ws + 2 * SZ_X + SZ_W);
  float2* partials = (float2*)(ws + 2 * SZ_X + 2 * SZ_W);
  float*  tgt      = (float*)(ws + 2 * SZ_X + 2 * SZ_W + (size_t)2 * NTILES * MROWS * 8);
  float*  logps    = (float*)(ws + 2 * SZ_X + 2 * SZ_W + (size_t)2 * NTILES * MROWS * 8 + 2 * MROWS * 4);

  cvt_all<<<dim3(2048), 256, 0, stream>>>((const float4*)x, (const float4*)rx,
                                          (const float4*)W, (const float4*)rW,
                                          (uint4*)xb, (uint4*)rxb, (uint4*)Wb, (uint4*)rWb);

  gemm_lse<<<dim3(4000, 2), 256, 0, stream>>>(xb, rxb, Wb, rWb, y, partials, tgt);
  rowred<<<dim3(8), 256, 0, stream>>>(partials, tgt, y, logps);
  finalk<<<dim3(1), 64, 0, stream>>>(logps, pref, out);
}

// Round 10
// 913.317 us; speedup vs baseline: 1.0837x; 1.0837x over previous
//
#include <hip/hip_runtime.h>
#include <hip/hip_bf16.h>

#define MROWS 4096      // B*T
#define KDIM 1024       // H (bytes per row in fp8)
#define NVOCAB 32000    // V
#define BM 256
#define BN 256
#define BKB 128                // K elems (=bytes, fp8) per group
#define NTILES (NVOCAB / BN)   // 125
#define KT (KDIM / BKB)        // 8 groups
#define BETA 0.1f

typedef __attribute__((ext_vector_type(4))) int i4v;
typedef __attribute__((ext_vector_type(8))) int i8v;
typedef __attribute__((ext_vector_type(16))) float f16v;

__device__ inline void gload16(const void* g, void* l) {
  __builtin_amdgcn_global_load_lds(
      (const __attribute__((address_space(1))) void*)g,
      (__attribute__((address_space(3))) void*)l, 16, 0, 0);
}

// fused fp32 -> fp8 e4m3 (OCP, sat) for all 4 tensors, 8 elems/thread
__global__ void cvt_all(const float4* __restrict__ x, const float4* __restrict__ rx,
                        const float4* __restrict__ W, const float4* __restrict__ rW,
                        uint2* __restrict__ xq, uint2* __restrict__ rxq,
                        uint2* __restrict__ Wq, uint2* __restrict__ rWq) {
  const int NX = MROWS * KDIM / 8;      // 524288
  const int NW = NVOCAB * KDIM / 8;     // 4096000
  const int total = 2 * NX + 2 * NW;
  for (int i = blockIdx.x * 256 + threadIdx.x; i < total; i += gridDim.x * 256) {
    const float4* s; uint2* d; int j;
    if (i < NX)               { s = x;  d = xq;  j = i; }
    else if (i < 2 * NX)      { s = rx; d = rxq; j = i - NX; }
    else if (i < 2 * NX + NW) { s = W;  d = Wq;  j = i - 2 * NX; }
    else                      { s = rW; d = rWq; j = i - 2 * NX - NW; }
    float4 a = s[2 * j], b = s[2 * j + 1];
    unsigned lo = __builtin_amdgcn_cvt_pk_fp8_f32(a.x, a.y, 0, false);
    lo = __builtin_amdgcn_cvt_pk_fp8_f32(a.z, a.w, lo, true);
    unsigned hi = __builtin_amdgcn_cvt_pk_fp8_f32(b.x, b.y, 0, false);
    hi = __builtin_amdgcn_cvt_pk_fp8_f32(b.z, b.w, hi, true);
    d[j] = make_uint2(lo, hi);
  }
}

// frag loader: lane's 32 fp8 = two 16B halves at +0 (k 0..15) and +1024 (k 16..31)
__device__ inline i8v ldfrag(const unsigned char* p) {
  i4v lo = *(const i4v*)p;
  i4v hi = *(const i4v*)(p + 1024);
  return __builtin_shufflevector(lo, hi, 0, 1, 2, 3, 4, 5, 6, 7);
}

// 256x256 GEMM, MX-fp8 32x32x64 MFMA (scale=1.0), BKB=128 (8 groups of 2 sub-K),
// 2-slot LDS ring (128 KB), stage-ahead-1, one vmcnt(0)+barrier trail per group,
// compiler-scheduled reads/MFMA. LDS fragment-contiguous:
//   addr = ks*16384 + sblk*2048 + h*1024 + lane*16
//   (sblk = 32-row block; lane l: row l&31, k-half l>>5; h = 16B half)
// grid = (2000, 2 models), block = 512 (8 waves 2x4, each 128x64 out)
__global__ __launch_bounds__(512, 2) void gemm_lse(
    const unsigned char* __restrict__ xq, const unsigned char* __restrict__ rxq,
    const unsigned char* __restrict__ Wq, const unsigned char* __restrict__ rWq,
    const int* __restrict__ y,
    float2* __restrict__ partials,  // [2][NTILES][MROWS]
    float* __restrict__ tgt)        // [2][MROWS]
{
  const int bid = blockIdx.x;       // 0..1999
  const int bz  = blockIdx.y;       // model
  // XCD banding: each XCD sweeps 4-mtile bands across ntiles (W panel reuse)
  const int lin   = (bid & 7) * 250 + (bid >> 3);
  const int mg    = lin / 500;
  const int rem   = lin % 500;
  const int ntile = rem >> 2;
  const int mtile = mg * 4 + (rem & 3);
  const int m0 = mtile * BM, n0 = ntile * BN;

  const unsigned char* A  = bz ? rxq : xq;
  const unsigned char* Bw = bz ? rWq : Wq;

  const int tid = threadIdx.x;
  const int lane = tid & 63;
  const int w = tid >> 6;            // 0..7
  const int wr = w >> 2, wc = w & 3; // 2 x 4 wave grid
  const int hi5 = lane >> 5;

  __shared__ __align__(16) unsigned char As[2][32768];
  __shared__ __align__(16) unsigned char Bs[2][32768];
  __shared__ int ys[BM];
  __shared__ float redM[4][BM];
  __shared__ float redS[4][BM];

  if (tid < BM) ys[tid] = y[m0 + tid];

  f16v acc[4][2];
#pragma unroll
  for (int i = 0; i < 4; ++i)
#pragma unroll
    for (int j = 0; j < 2; ++j) acc[i][j] = (f16v)(0.f);

  // staging decode: chunk c = j*512+tid -> LDS byte c*16;
  // c = ks*1024 + sblk*128 + h*64 + l: row sblk*32+(l&31), k ks*64+(l>>5)*32+h*16
  const unsigned char* srcA[4];
  const unsigned char* srcB[4];
#pragma unroll
  for (int j = 0; j < 4; ++j) {
    int c = j * 512 + tid;
    int ks = c >> 10, cc = c & 1023;
    int sblk = cc >> 7, c3 = cc & 127;
    int h = (c3 >> 6) & 1, l = c3 & 63;
    int row = sblk * 32 + (l & 31);
    int kk = ks * 64 + (l >> 5) * 32 + h * 16;
    srcA[j] = A  + (size_t)(m0 + row) * KDIM + kk;
    srcB[j] = Bw + (size_t)(n0 + row) * KDIM + kk;
  }

#define STAGE(s)                                                     \
  {                                                                  \
    _Pragma("unroll")                                                \
    for (int j = 0; j < 4; ++j) {                                    \
      gload16(srcA[j], &As[s][(j * 512 + tid) * 16]);                \
      gload16(srcB[j], &Bs[s][(j * 512 + tid) * 16]);                \
      srcA[j] += BKB; srcB[j] += BKB;                                \
    }                                                                \
  }

  // prologue: stage tile 0 -> slot 0
  STAGE(0);
  asm volatile("s_waitcnt vmcnt(0)" ::: "memory");
  __builtin_amdgcn_s_barrier();

  // Group t: 2 sub-K steps (K=64 each) on slot t&1; stage t+1 -> other slot.
#pragma unroll 1
  for (int t = 0; t < KT; ++t) {
    const unsigned char* baseA = &As[t & 1][lane * 16];
    const unsigned char* baseB = &Bs[t & 1][lane * 16];
    i8v af[4], bf[2];
    // ---- sub-step ks=0 ----
#pragma unroll
    for (int mi = 0; mi < 4; ++mi) af[mi] = ldfrag(baseA + (wr * 4 + mi) * 2048);
#pragma unroll
    for (int ni = 0; ni < 2; ++ni) bf[ni] = ldfrag(baseB + (wc * 2 + ni) * 2048);
    if (t < KT - 1) STAGE((t + 1) & 1);
#pragma unroll
    for (int mi = 0; mi < 4; ++mi)
#pragma unroll
      for (int ni = 0; ni < 2; ++ni)
        acc[mi][ni] = __builtin_amdgcn_mfma_scale_f32_32x32x64_f8f6f4(
            af[mi], bf[ni], acc[mi][ni], 0, 0, 0, 127, 0, 127);
    // ---- sub-step ks=1 ----
#pragma unroll
    for (int mi = 0; mi < 4; ++mi) af[mi] = ldfrag(baseA + 16384 + (wr * 4 + mi) * 2048);
#pragma unroll
    for (int ni = 0; ni < 2; ++ni) bf[ni] = ldfrag(baseB + 16384 + (wc * 2 + ni) * 2048);
#pragma unroll
    for (int mi = 0; mi < 4; ++mi)
#pragma unroll
      for (int ni = 0; ni < 2; ++ni)
        acc[mi][ni] = __builtin_amdgcn_mfma_scale_f32_32x32x64_f8f6f4(
            af[mi], bf[ni], acc[mi][ni], 0, 0, 0, 127, 0, 127);
    if (t < KT - 1) {
      asm volatile("s_waitcnt vmcnt(0)" ::: "memory");
      __builtin_amdgcn_s_barrier();
    }
  }
#undef STAGE

  // Epilogue: per-row (max, sumexp) over this block's 256 cols + target gather.
  // 32x32 D layout (HW-verified r3): col = lane&31, row = (r&3)+8*(r>>2)+4*(lane>>5)
#pragma unroll
  for (int mi = 0; mi < 4; ++mi) {
#pragma unroll
    for (int r = 0; r < 16; ++r) {
      float v0 = acc[mi][0][r], v1 = acc[mi][1][r];
      float mx = fmaxf(v0, v1);
#pragma unroll
      for (int d = 1; d < 32; d <<= 1) mx = fmaxf(mx, __shfl_xor(mx, d));
      float ex = __expf(v0 - mx) + __expf(v1 - mx);
#pragma unroll
      for (int d = 1; d < 32; d <<= 1) ex += __shfl_xor(ex, d);
      int rowInBlock = wr * 128 + mi * 32 + (r & 3) + 8 * (r >> 2) + 4 * hi5;
      if ((lane & 31) == 0) { redM[wc][rowInBlock] = mx; redS[wc][rowInBlock] = ex; }
      int yv = ys[rowInBlock];
      int cl = yv - (n0 + wc * 64);
      if (cl >= 0 && cl < 64 && (cl & 31) == (lane & 31))
        tgt[(size_t)bz * MROWS + m0 + rowInBlock] = (cl >> 5) ? v1 : v0;
    }
  }
  __syncthreads();
  if (tid < BM) {
    float M = redM[0][tid], S = redS[0][tid];
#pragma unroll
    for (int c = 1; c < 4; ++c) {
      float m2 = redM[c][tid], s2 = redS[c][tid];
      float Mn = fmaxf(M, m2);
      S = S * __expf(M - Mn) + s2 * __expf(m2 - Mn);
      M = Mn;
    }
    partials[((size_t)bz * NTILES + ntile) * MROWS + m0 + tid] = make_float2(M, S);
  }
}

// merge partials per row -> lse -> per-example mean target logp
__global__ void rowred(const float2* __restrict__ partials, const float* __restrict__ tgt,
                       const int* __restrict__ y, float* __restrict__ logps) {
  const int model = blockIdx.x >> 2;
  const int b = blockIdx.x & 3;
  const int tid = threadIdx.x;
  float sum = 0.f, cnt = 0.f;
  for (int t = tid; t < 1024; t += 256) {
    const int row = b * 1024 + t;
    float M = -INFINITY, S = 0.f;
    for (int j = 0; j < NTILES; ++j) {
      float2 v = partials[((size_t)model * NTILES + j) * MROWS + row];
      float Mn = fmaxf(M, v.x);
      S = S * __expf(M - Mn) + v.y * __expf(v.x - Mn);
      M = Mn;
    }
    int yv = y[row];
    if (yv != -100) {
      sum += tgt[(size_t)model * MROWS + row] - (M + __logf(S));
      cnt += 1.f;
    }
  }
  __shared__ float sS[4], sC[4];
#pragma unroll
  for (int d = 1; d < 64; d <<= 1) { sum += __shfl_xor(sum, d); cnt += __shfl_xor(cnt, d); }
  int w = tid >> 6;
  if ((tid & 63) == 0) { sS[w] = sum; sC[w] = cnt; }
  __syncthreads();
  if (tid == 0) {
    float s = 0.f, c = 0.f;
    for (int i = 0; i < 4; ++i) { s += sS[i]; c += sC[i]; }
    logps[blockIdx.x] = s / c;
  }
}

__global__ void finalk(const float* __restrict__ logps, const int* __restrict__ pref,
                       float* __restrict__ out) {
  if (threadIdx.x == 0 && blockIdx.x == 0) {
    float acc = 0.f;
    for (int b = 0; b < 4; ++b) {
      float lr = logps[b] - logps[4 + b];   // policy - ref
      float z = BETA * lr;
      float sig = 1.f / (1.f + __expf(-z));
      acc += (pref[b] != 0) ? (1.f - sig) : sig;
    }
    out[0] = acc * 0.25f;
  }
}

extern "C" void kernel_launch(void* const* d_in, const int* in_sizes, int n_in,
                              void* d_out, int out_size, void* d_ws, size_t ws_size,
                              hipStream_t stream) {
  const float* x    = (const float*)d_in[0];
  const float* rx   = (const float*)d_in[1];
  const int*   y    = (const int*)d_in[2];
  const int*   pref = (const int*)d_in[3];
  const float* W    = (const float*)d_in[4];
  const float* rW   = (const float*)d_in[5];
  float* out = (float*)d_out;

  char* ws = (char*)d_ws;
  const size_t SZ_X = (size_t)MROWS * KDIM;        // 4,194,304 (fp8)
  const size_t SZ_W = (size_t)NVOCAB * KDIM;       // 32,768,000 (fp8)
  unsigned char* xq  = (unsigned char*)(ws);
  unsigned char* rxq = (unsigned char*)(ws + SZ_X);
  unsigned char* Wq  = (unsigned char*)(ws + 2 * SZ_X);
  unsigned char* rWq = (unsigned char*)(ws + 2 * SZ_X + SZ_W);
  float2* partials = (float2*)(ws + 2 * SZ_X + 2 * SZ_W);
  float*  tgt      = (float*)(ws + 2 * SZ_X + 2 * SZ_W + (size_t)2 * NTILES * MROWS * 8);
  float*  logps    = (float*)(ws + 2 * SZ_X + 2 * SZ_W + (size_t)2 * NTILES * MROWS * 8 + 2 * MROWS * 4);

  cvt_all<<<dim3(2048), 256, 0, stream>>>((const float4*)x, (const float4*)rx,
                                          (const float4*)W, (const float4*)rW,
                                          (uint2*)xq, (uint2*)rxq, (uint2*)Wq, (uint2*)rWq);

  gemm_lse<<<dim3(2000, 2), 512, 0, stream>>>(xq, rxq, Wq, rWq, y, partials, tgt);
  rowred<<<dim3(8), 256, 0, stream>>>(partials, tgt, y, logps);
  finalk<<<dim3(1), 64, 0, stream>>>(logps, pref, out);
}

// Round 11
// 667.886 us; speedup vs baseline: 1.4819x; 1.3675x over previous
//
#include <hip/hip_runtime.h>
#include <hip/hip_bf16.h>

#define MROWS 4096      // B*T
#define KDIM 1024       // H
#define NVOCAB 32000    // V
#define BM 128
#define BN 128
#define NTILES (NVOCAB / BN)   // 250
#define MTILES (MROWS / BM)    // 32
#define KT 16                  // K-steps of 64
#define BETA 0.1f

typedef __attribute__((ext_vector_type(4))) int i4v;
typedef __attribute__((ext_vector_type(8))) int i8v;
typedef __attribute__((ext_vector_type(16))) float f16v;

__device__ inline void gload16(const void* g, void* l) {
  __builtin_amdgcn_global_load_lds(
      (const __attribute__((address_space(1))) void*)g,
      (__attribute__((address_space(3))) void*)l, 16, 0, 0);
}

// fp32 -> fp8 e4m3 pack into LDS-image layout.
// Tensor of R rows (row-major, 1024 f32 cols) -> tiles of 128 rows; per tile,
// per step (64 cols), an 8192-B image; chunk c (16 B) decode:
//   blk=c>>7, r2=c&127, h=(r2>>6)&1, l=r2&63
//   row = tile*128 + blk*32 + (l&31), col = step*64 + (l>>5)*32 + h*16
// Packed addr = ((tile*16 + step)*512 + c)*16  -> GEMM staging is fully linear.
__global__ void cvt_all(const float4* __restrict__ x, const float4* __restrict__ rx,
                        const float4* __restrict__ W, const float4* __restrict__ rW,
                        uint4* __restrict__ xq, uint4* __restrict__ rxq,
                        uint4* __restrict__ Wq, uint4* __restrict__ rWq) {
  const int NA = MTILES * KT * 512;    // 262144 chunks
  const int NW = NTILES * KT * 512;    // 2048000 chunks
  const int total = 2 * NA + 2 * NW;
  for (int g = blockIdx.x * 256 + threadIdx.x; g < total; g += gridDim.x * 256) {
    const float4* s; uint4* d; int j;
    if (g < NA)               { s = x;  d = xq;  j = g; }
    else if (g < 2 * NA)      { s = rx; d = rxq; j = g - NA; }
    else if (g < 2 * NA + NW) { s = W;  d = Wq;  j = g - 2 * NA; }
    else                      { s = rW; d = rWq; j = g - 2 * NA - NW; }
    const int tile = j >> 13;
    const int rem  = j & 8191;
    const int step = rem >> 9;
    const int c    = rem & 511;
    const int blk = c >> 7, r2 = c & 127;
    const int h = (r2 >> 6) & 1, l = r2 & 63;
    const int row = tile * 128 + blk * 32 + (l & 31);
    const int col = step * 64 + (l >> 5) * 32 + h * 16;
    const float4* p = s + ((size_t)row * KDIM + col) / 4;
    float4 a = p[0], b = p[1], e = p[2], f = p[3];
    unsigned w0 = __builtin_amdgcn_cvt_pk_fp8_f32(a.x, a.y, 0, false);
    w0 = __builtin_amdgcn_cvt_pk_fp8_f32(a.z, a.w, w0, true);
    unsigned w1 = __builtin_amdgcn_cvt_pk_fp8_f32(b.x, b.y, 0, false);
    w1 = __builtin_amdgcn_cvt_pk_fp8_f32(b.z, b.w, w1, true);
    unsigned w2 = __builtin_amdgcn_cvt_pk_fp8_f32(e.x, e.y, 0, false);
    w2 = __builtin_amdgcn_cvt_pk_fp8_f32(e.z, e.w, w2, true);
    unsigned w3 = __builtin_amdgcn_cvt_pk_fp8_f32(f.x, f.y, 0, false);
    w3 = __builtin_amdgcn_cvt_pk_fp8_f32(f.z, f.w, w3, true);
    d[j] = make_uint4(w0, w1, w2, w3);
  }
}

// frag loader: lane's 32 fp8 = 16B at +0 (k 0..15) and +1024 (k 16..31)
__device__ inline i8v ldfrag(const unsigned char* p) {
  i4v lo = *(const i4v*)p;
  i4v hi = *(const i4v*)(p + 1024);
  return __builtin_shufflevector(lo, hi, 0, 1, 2, 3, 4, 5, 6, 7);
}

// 128x128 GEMM, MX-fp8 32x32x64 (scale=1.0), pre-packed operands (linear
// staging), 2-slot dbuf, plain __syncthreads, 4 blocks/CU TLP (r1 regime).
// grid = (8000, 2 models), block = 256 (4 waves 2x2, each 64x64 out)
__global__ __launch_bounds__(256, 4) void gemm_lse(
    const unsigned char* __restrict__ xq, const unsigned char* __restrict__ rxq,
    const unsigned char* __restrict__ Wq, const unsigned char* __restrict__ rWq,
    const int* __restrict__ y,
    float2* __restrict__ partials,  // [2][NTILES][MROWS]
    float* __restrict__ tgt)        // [2][MROWS]
{
  const int bid = blockIdx.x;       // 0..7999
  const int bz  = blockIdx.y;       // model
  // XCD banding: XCD x owns mtiles x*4..x*4+3, sweeps ntiles (A L2-resident)
  const int xcd   = bid & 7;
  const int idx   = bid >> 3;       // 0..999
  const int ntile = idx % NTILES;
  const int mtile = xcd * 4 + idx / NTILES;
  const int m0 = mtile * BM, n0 = ntile * BN;

  const unsigned char* Ap = (bz ? rxq : xq) + (size_t)mtile * (KT * 8192);
  const unsigned char* Bp = (bz ? rWq : Wq) + (size_t)ntile * (KT * 8192);

  const int tid = threadIdx.x;
  const int lane = tid & 63;
  const int w = tid >> 6;            // 0..3
  const int wr = w >> 1, wc = w & 1; // 2 x 2 wave grid
  const int l31 = lane & 31, hi5 = lane >> 5;

  __shared__ __align__(16) unsigned char As[2][8192];
  __shared__ __align__(16) unsigned char Bs[2][8192];
  __shared__ int ys[BM];
  __shared__ float redM[2][BM];
  __shared__ float redS[2][BM];

  if (tid < BM) ys[tid] = y[m0 + tid];

  f16v acc[2][2];
#pragma unroll
  for (int i = 0; i < 2; ++i)
#pragma unroll
    for (int j = 0; j < 2; ++j) acc[i][j] = (f16v)(0.f);

#define STAGE(t, s)                                                     \
  {                                                                     \
    const unsigned char* a = Ap + (t) * 8192 + tid * 16;                \
    const unsigned char* b = Bp + (t) * 8192 + tid * 16;                \
    gload16(a,        &As[s][tid * 16]);                                \
    gload16(a + 4096, &As[s][tid * 16 + 4096]);                        \
    gload16(b,        &Bs[s][tid * 16]);                                \
    gload16(b + 4096, &Bs[s][tid * 16 + 4096]);                        \
  }

  // prologue
  STAGE(0, 0);
  __syncthreads();

#pragma unroll 1
  for (int t = 0; t < KT; ++t) {
    const unsigned char* baseA = &As[t & 1][lane * 16];
    const unsigned char* baseB = &Bs[t & 1][lane * 16];
    i8v af[2], bf[2];
#pragma unroll
    for (int mi = 0; mi < 2; ++mi) af[mi] = ldfrag(baseA + (wr * 2 + mi) * 2048);
#pragma unroll
    for (int ni = 0; ni < 2; ++ni) bf[ni] = ldfrag(baseB + (wc * 2 + ni) * 2048);
    if (t + 1 < KT) STAGE(t + 1, (t + 1) & 1);
#pragma unroll
    for (int mi = 0; mi < 2; ++mi)
#pragma unroll
      for (int ni = 0; ni < 2; ++ni)
        acc[mi][ni] = __builtin_amdgcn_mfma_scale_f32_32x32x64_f8f6f4(
            af[mi], bf[ni], acc[mi][ni], 0, 0, 0, 127, 0, 127);
    __syncthreads();   // drains stage(t+1) + this step's reads; TLP covers
  }
#undef STAGE

  // Epilogue: per-row (max,sumexp) over this block's 128 cols + target gather.
  // 32x32 D layout (HW-verified r3/r10): col = lane&31, row = (r&3)+8*(r>>2)+4*hi5
#pragma unroll
  for (int mi = 0; mi < 2; ++mi) {
#pragma unroll
    for (int r = 0; r < 16; ++r) {
      float v0 = acc[mi][0][r], v1 = acc[mi][1][r];
      float mx = fmaxf(v0, v1);
#pragma unroll
      for (int d = 1; d < 32; d <<= 1) mx = fmaxf(mx, __shfl_xor(mx, d));
      float ex = __expf(v0 - mx) + __expf(v1 - mx);
#pragma unroll
      for (int d = 1; d < 32; d <<= 1) ex += __shfl_xor(ex, d);
      int rowInBlock = wr * 64 + mi * 32 + (r & 3) + 8 * (r >> 2) + 4 * hi5;
      if (l31 == 0) { redM[wc][rowInBlock] = mx; redS[wc][rowInBlock] = ex; }
      int yv = ys[rowInBlock];
      int cl = yv - (n0 + wc * 64);
      if (cl >= 0 && cl < 64 && (cl & 31) == l31)
        tgt[(size_t)bz * MROWS + m0 + rowInBlock] = (cl >> 5) ? v1 : v0;
    }
  }
  __syncthreads();
  if (tid < BM) {
    float ma = redM[0][tid], mb = redM[1][tid];
    float sa = redS[0][tid], sb = redS[1][tid];
    float M = fmaxf(ma, mb);
    float S = sa * __expf(ma - M) + sb * __expf(mb - M);
    partials[((size_t)bz * NTILES + ntile) * MROWS + m0 + tid] = make_float2(M, S);
  }
}

// merge partials per row -> lse -> per-example mean target logp
__global__ void rowred(const float2* __restrict__ partials, const float* __restrict__ tgt,
                       const int* __restrict__ y, float* __restrict__ logps) {
  const int model = blockIdx.x >> 2;
  const int b = blockIdx.x & 3;
  const int tid = threadIdx.x;
  float sum = 0.f, cnt = 0.f;
  for (int t = tid; t < 1024; t += 256) {
    const int row = b * 1024 + t;
    float M = -INFINITY, S = 0.f;
    for (int j = 0; j < NTILES; ++j) {
      float2 v = partials[((size_t)model * NTILES + j) * MROWS + row];
      float Mn = fmaxf(M, v.x);
      S = S * __expf(M - Mn) + v.y * __expf(v.x - Mn);
      M = Mn;
    }
    int yv = y[row];
    if (yv != -100) {
      sum += tgt[(size_t)model * MROWS + row] - (M + __logf(S));
      cnt += 1.f;
    }
  }
  __shared__ float sS[4], sC[4];
#pragma unroll
  for (int d = 1; d < 64; d <<= 1) { sum += __shfl_xor(sum, d); cnt += __shfl_xor(cnt, d); }
  int w = tid >> 6;
  if ((tid & 63) == 0) { sS[w] = sum; sC[w] = cnt; }
  __syncthreads();
  if (tid == 0) {
    float s = 0.f, c = 0.f;
    for (int i = 0; i < 4; ++i) { s += sS[i]; c += sC[i]; }
    logps[blockIdx.x] = s / c;
  }
}

__global__ void finalk(const float* __restrict__ logps, const int* __restrict__ pref,
                       float* __restrict__ out) {
  if (threadIdx.x == 0 && blockIdx.x == 0) {
    float acc = 0.f;
    for (int b = 0; b < 4; ++b) {
      float lr = logps[b] - logps[4 + b];   // policy - ref
      float z = BETA * lr;
      float sig = 1.f / (1.f + __expf(-z));
      acc += (pref[b] != 0) ? (1.f - sig) : sig;
    }
    out[0] = acc * 0.25f;
  }
}

extern "C" void kernel_launch(void* const* d_in, const int* in_sizes, int n_in,
                              void* d_out, int out_size, void* d_ws, size_t ws_size,
                              hipStream_t stream) {
  const float* x    = (const float*)d_in[0];
  const float* rx   = (const float*)d_in[1];
  const int*   y    = (const int*)d_in[2];
  const int*   pref = (const int*)d_in[3];
  const float* W    = (const float*)d_in[4];
  const float* rW   = (const float*)d_in[5];
  float* out = (float*)d_out;

  char* ws = (char*)d_ws;
  const size_t SZ_X = (size_t)MROWS * KDIM;        // 4 MB (fp8 packed)
  const size_t SZ_W = (size_t)NVOCAB * KDIM;       // 32 MB (fp8 packed)
  unsigned char* xq  = (unsigned char*)(ws);
  unsigned char* rxq = (unsigned char*)(ws + SZ_X);
  unsigned char* Wq  = (unsigned char*)(ws + 2 * SZ_X);
  unsigned char* rWq = (unsigned char*)(ws + 2 * SZ_X + SZ_W);
  float2* partials = (float2*)(ws + 2 * SZ_X + 2 * SZ_W);
  float*  tgt      = (float*)(ws + 2 * SZ_X + 2 * SZ_W + (size_t)2 * NTILES * MROWS * 8);
  float*  logps    = (float*)(ws + 2 * SZ_X + 2 * SZ_W + (size_t)2 * NTILES * MROWS * 8 + 2 * MROWS * 4);

  cvt_all<<<dim3(2048), 256, 0, stream>>>((const float4*)x, (const float4*)rx,
                                          (const float4*)W, (const float4*)rW,
                                          (uint4*)xq, (uint4*)rxq, (uint4*)Wq, (uint4*)rWq);

  gemm_lse<<<dim3(8000, 2), 256, 0, stream>>>(xq, rxq, Wq, rWq, y, partials, tgt);
  rowred<<<dim3(8), 256, 0, stream>>>(partials, tgt, y, logps);
  finalk<<<dim3(1), 64, 0, stream>>>(logps, pref, out);
}